// Round 5
// baseline (34.850 us; speedup 1.0000x reference)
//
#include <hip/hip_runtime.h>
#include <math.h>

#define TPB  256
#define NBLK 32
#define CAP  2048          // candidate capacity in LDS (expected ~40 used)
#define BMW_MAX 2048       // bitmap words -> supports n <= 65536

typedef unsigned long long ull;

__device__ __forceinline__ ull umin64(ull a, ull b) { return a < b ? a : b; }
__device__ __forceinline__ ull umax64(ull a, ull b) { return a > b ? a : b; }

// Branchless order-statistic merge of two ascending 5-lists (64-bit keys).
// Keys are ((dist_bits)<<32)|orig_j -> unique, total order, exact
// jax.lax.top_k tie-break (lower original index wins).
__device__ __forceinline__ void merge5u(ull& a0, ull& a1, ull& a2, ull& a3, ull& a4,
                                        ull b0, ull b1, ull b2, ull b3, ull b4) {
    ull m0 = umin64(a0, b0);
    ull m1 = umin64(umin64(a1, b1), umax64(a0, b0));
    ull m2 = umin64(umin64(a2, b2), umin64(umax64(a0, b1), umax64(a1, b0)));
    ull m3 = umin64(umin64(a3, b3),
                    umin64(umin64(umax64(a0, b2), umax64(a1, b1)), umax64(a2, b0)));
    ull m4 = umin64(umin64(a4, b4),
                    umin64(umin64(umax64(a0, b3), umax64(a1, b2)),
                           umin64(umax64(a2, b1), umax64(a3, b0))));
    a0 = m0; a1 = m1; a2 = m2; a3 = m3; a4 = m4;
}

// float (value-only) variant, used for the threshold tau
__device__ __forceinline__ void merge5f(float& a0, float& a1, float& a2, float& a3, float& a4,
                                        float b0, float b1, float b2, float b3, float b4) {
    float m0 = fminf(a0, b0);
    float m1 = fminf(fminf(a1, b1), fmaxf(a0, b0));
    float m2 = fminf(fminf(a2, b2), fminf(fmaxf(a0, b1), fmaxf(a1, b0)));
    float m3 = fminf(fminf(a3, b3),
                     fminf(fminf(fmaxf(a0, b2), fmaxf(a1, b1)), fmaxf(a2, b0)));
    float m4 = fminf(fminf(a4, b4),
                     fminf(fminf(fmaxf(a0, b3), fmaxf(a1, b2)),
                           fminf(fmaxf(a2, b1), fmaxf(a3, b0))));
    a0 = m0; a1 = m1; a2 = m2; a3 = m3; a4 = m4;
}

__device__ __forceinline__ void insert5u(ull key, ull& k0, ull& k1, ull& k2, ull& k3, ull& k4) {
    if (key < k4) {
        k4 = key;
        ull t;
        if (k4 < k3) { t = k3; k3 = k4; k4 = t; }
        if (k3 < k2) { t = k2; k2 = k3; k3 = t; }
        if (k2 < k1) { t = k1; k1 = k2; k2 = t; }
        if (k1 < k0) { t = k0; k0 = k1; k1 = t; }
    }
}

#define BFLYU(kk0,kk1,kk2,kk3,kk4,WIDTH)                            \
    for (int mask_ = 1; mask_ < (WIDTH); mask_ <<= 1) {             \
        ull b0_ = __shfl_xor(kk0, mask_, 64);                       \
        ull b1_ = __shfl_xor(kk1, mask_, 64);                       \
        ull b2_ = __shfl_xor(kk2, mask_, 64);                       \
        ull b3_ = __shfl_xor(kk3, mask_, 64);                       \
        ull b4_ = __shfl_xor(kk4, mask_, 64);                       \
        merge5u(kk0, kk1, kk2, kk3, kk4, b0_, b1_, b2_, b3_, b4_);  \
    }

#define BFLYF(kk0,kk1,kk2,kk3,kk4,WIDTH)                            \
    for (int mask_ = 1; mask_ < (WIDTH); mask_ <<= 1) {             \
        float b0_ = __shfl_xor(kk0, mask_, 64);                     \
        float b1_ = __shfl_xor(kk1, mask_, 64);                     \
        float b2_ = __shfl_xor(kk2, mask_, 64);                     \
        float b3_ = __shfl_xor(kk3, mask_, 64);                     \
        float b4_ = __shfl_xor(kk4, mask_, 64);                     \
        merge5f(kk0, kk1, kk2, kk3, kk4, b0_, b1_, b2_, b3_, b4_);  \
    }

// ---------------------------------------------------------------------------
// Single kernel, NBLK independent blocks. Every block redundantly computes
// the exact imputed scalar v (cheap, ~40 candidates), then writes its own
// disjoint slice of out = missing ? v : X. No workspace, no cross-block sync.
//
// Threshold correctness: tau2 = 5th-smallest of per-thread min(x^2 over its
// observed range). At most 4 per-thread minima can be < the global 5th-
// smallest observed x^2 (= r0^2), so tau2 >= r0^2. Reachability bound
// (v0 = 0): iter-1 picks |x|<=r0 -> |v1|<=r0; d5(v1)<=2r0 -> picks |x|<=3r0
// -> |v2|<=3r0; d5(v2)<=4r0 -> picks |x|<=7r0. Filter keeps x^2 <= 64*tau2
// >= (8*r0)^2 -> superset of everything selectable. Overflow -> exact
// full-scan fallback (same semantics, slower).
// ---------------------------------------------------------------------------
__global__ void __launch_bounds__(TPB) knn_all_kernel(
    const float* __restrict__ X, const int* __restrict__ miss_idx,
    float* __restrict__ out, int n, int n_miss, int n_obs)
{
    __shared__ unsigned bm[BMW_MAX];           // missing bitmap (4 KB @ n=32768)
    __shared__ uint2    cand[CAP];             // (x_bits, j) candidates
    __shared__ int      cnt_sh;
    __shared__ float    skf[(TPB / 64) * 5];   // tau merge scratch
    __shared__ ull      sku[(TPB / 64) * 5];   // key merge scratch
    __shared__ ull      wk[5];
    __shared__ float    vals[5];
    __shared__ float    thr_sh, v_sh;
    __shared__ int      wsum[TPB / 64];

    const int tid  = threadIdx.x;
    const int b    = blockIdx.x;
    const int wid  = tid >> 6;
    const int lane = tid & 63;
    const int NW   = TPB / 64;
    const int bmw  = (n + 31) >> 5;

    // ---- phase 0: zero bitmap + counter ----
    for (int w = tid; w < bmw; w += TPB) bm[w] = 0u;
    if (tid == 0) cnt_sh = 0;
    __syncthreads();

    // ---- phase 1: set missing bits ----
    for (int e = tid; e < n_miss; e += TPB) {
        int p = miss_idx[e];
        atomicOr(&bm[p >> 5], 1u << (p & 31));
    }
    __syncthreads();

    // per-thread contiguous, word-aligned range
    int per = ((n + TPB - 1) / TPB + 31) & ~31;       // 128 for n=32768
    const int rbeg = tid * per;
    const int rend = min(n, rbeg + per);

    // ---- phase 2: pass A — per-thread min x^2 over observed + obs count ----
    float minxx = INFINITY;
    int   myobs = 0;
    {
        int p = rbeg;
        for (; p + 3 < rend; p += 4) {
            float4 xx = *reinterpret_cast<const float4*>(X + p);
            unsigned bits = (bm[p >> 5] >> (p & 31)) & 0xFu;
            if (!(bits & 1u)) { ++myobs; minxx = fminf(minxx, xx.x * xx.x); }
            if (!(bits & 2u)) { ++myobs; minxx = fminf(minxx, xx.y * xx.y); }
            if (!(bits & 4u)) { ++myobs; minxx = fminf(minxx, xx.z * xx.z); }
            if (!(bits & 8u)) { ++myobs; minxx = fminf(minxx, xx.w * xx.w); }
        }
        for (; p < rend; ++p) {
            bool miss = (bm[p >> 5] >> (p & 31)) & 1u;
            if (!miss) { ++myobs; float x = X[p]; minxx = fminf(minxx, x * x); }
        }
    }

    // tau2 = 5th smallest of the 256 per-thread minima
    {
        float t0 = minxx, t1 = INFINITY, t2 = INFINITY, t3 = INFINITY, t4 = INFINITY;
        BFLYF(t0, t1, t2, t3, t4, 64)
        if (lane == 0) {
            skf[wid * 5 + 0] = t0; skf[wid * 5 + 1] = t1; skf[wid * 5 + 2] = t2;
            skf[wid * 5 + 3] = t3; skf[wid * 5 + 4] = t4;
        }
    }
    // wave-prefix of obs counts (for exact original index j)
    int inc = myobs;
    for (int d = 1; d < 64; d <<= 1) {
        int o = __shfl_up(inc, d, 64);
        if (lane >= d) inc += o;
    }
    if (lane == 63) wsum[wid] = inc;
    __syncthreads();

    if (wid == 0) {
        float g0 = INFINITY, g1 = INFINITY, g2 = INFINITY, g3 = INFINITY, g4 = INFINITY;
        if (lane < NW) {
            g0 = skf[lane * 5 + 0]; g1 = skf[lane * 5 + 1]; g2 = skf[lane * 5 + 2];
            g3 = skf[lane * 5 + 3]; g4 = skf[lane * 5 + 4];
        }
        BFLYF(g0, g1, g2, g3, g4, NW)
        if (lane == 0) thr_sh = 64.0f * g4;    // (8*tau)^2; inf -> keep all -> fallback
    }
    __syncthreads();
    const float thr = thr_sh;
    int jbase = inc - myobs;
    for (int w = 0; w < wid; ++w) jbase += wsum[w];

    // ---- phase 3: pass B — collect candidates (x^2 <= thr) with exact j ----
    {
        int j = jbase;
        int p = rbeg;
        for (; p + 3 < rend; p += 4) {
            float4 xx = *reinterpret_cast<const float4*>(X + p);
            unsigned bits = (bm[p >> 5] >> (p & 31)) & 0xFu;
            float c4[4] = {xx.x, xx.y, xx.z, xx.w};
#pragma unroll
            for (int c = 0; c < 4; ++c) {
                if (!(bits & (1u << c))) {
                    float x = c4[c];
                    if (x * x <= thr) {
                        int s = atomicAdd(&cnt_sh, 1);
                        if (s < CAP) cand[s] = make_uint2(__float_as_uint(x), (unsigned)j);
                    }
                    ++j;
                }
            }
        }
        for (; p < rend; ++p) {
            bool miss = (bm[p >> 5] >> (p & 31)) & 1u;
            if (!miss) {
                float x = X[p];
                if (x * x <= thr) {
                    int s = atomicAdd(&cnt_sh, 1);
                    if (s < CAP) cand[s] = make_uint2(__float_as_uint(x), (unsigned)j);
                }
                ++j;
            }
        }
    }
    __syncthreads();
    const int  C    = cnt_sh;                   // deterministic (order-independent)
    const bool fast = (C >= 5) && (C <= CAP);

    // ---- phase 4: 3 exact fixed-point iterations ----
    float v = 0.0f;  // reference inits missing entries to 0
    for (int it = 0; it < 3; ++it) {
        ull k0 = ~0ull, k1 = ~0ull, k2 = ~0ull, k3 = ~0ull, k4 = ~0ull;
        if (fast) {
            for (int e = tid; e < C; e += TPB) {
                uint2 ce = cand[e];
                float x = __uint_as_float(ce.x);
                float diff = v - x;
                float d = diff * diff;
                insert5u(((ull)__float_as_uint(d) << 32) | (ull)ce.y, k0, k1, k2, k3, k4);
            }
        } else {
            // exact full-scan fallback (never expected on this data)
            int j = jbase;
            for (int p = rbeg; p < rend; ++p) {
                bool miss = (bm[p >> 5] >> (p & 31)) & 1u;
                if (!miss) {
                    float x = X[p];
                    float diff = v - x;
                    float d = diff * diff;
                    insert5u(((ull)__float_as_uint(d) << 32) | (unsigned)j, k0, k1, k2, k3, k4);
                    ++j;
                }
            }
        }
        BFLYU(k0, k1, k2, k3, k4, 64)
        if (lane == 0) {
            sku[wid * 5 + 0] = k0; sku[wid * 5 + 1] = k1; sku[wid * 5 + 2] = k2;
            sku[wid * 5 + 3] = k3; sku[wid * 5 + 4] = k4;
        }
        __syncthreads();
        if (wid == 0) {
            ull g0 = ~0ull, g1 = ~0ull, g2 = ~0ull, g3 = ~0ull, g4 = ~0ull;
            if (lane < NW) {
                g0 = sku[lane * 5 + 0]; g1 = sku[lane * 5 + 1]; g2 = sku[lane * 5 + 2];
                g3 = sku[lane * 5 + 3]; g4 = sku[lane * 5 + 4];
            }
            BFLYU(g0, g1, g2, g3, g4, NW)
            if (lane == 0) { wk[0] = g0; wk[1] = g1; wk[2] = g2; wk[3] = g3; wk[4] = g4; }
        }
        __syncthreads();
        // winner-value lookup by exact j match (unique j -> one writer each)
        unsigned wj0 = (unsigned)(wk[0] & 0xFFFFFFFFull);
        unsigned wj1 = (unsigned)(wk[1] & 0xFFFFFFFFull);
        unsigned wj2 = (unsigned)(wk[2] & 0xFFFFFFFFull);
        unsigned wj3 = (unsigned)(wk[3] & 0xFFFFFFFFull);
        unsigned wj4 = (unsigned)(wk[4] & 0xFFFFFFFFull);
        if (fast) {
            for (int e = tid; e < C; e += TPB) {
                uint2 ce = cand[e];
                float x = __uint_as_float(ce.x);
                if (ce.y == wj0) vals[0] = x;
                if (ce.y == wj1) vals[1] = x;
                if (ce.y == wj2) vals[2] = x;
                if (ce.y == wj3) vals[3] = x;
                if (ce.y == wj4) vals[4] = x;
            }
        } else {
            int j = jbase;
            for (int p = rbeg; p < rend; ++p) {
                bool miss = (bm[p >> 5] >> (p & 31)) & 1u;
                if (!miss) {
                    float x = X[p];
                    unsigned ju = (unsigned)j;
                    if (ju == wj0) vals[0] = x;
                    if (ju == wj1) vals[1] = x;
                    if (ju == wj2) vals[2] = x;
                    if (ju == wj3) vals[3] = x;
                    if (ju == wj4) vals[4] = x;
                    ++j;
                }
            }
        }
        __syncthreads();
        if (tid == 0) {
            // ascending (dist, idx) order — matches reference sum order exactly
            float s = vals[0]; s += vals[1]; s += vals[2]; s += vals[3]; s += vals[4];
            v_sh = s * 0.2f;
        }
        __syncthreads();
        v = v_sh;
        __syncthreads();   // sku/vals safely reusable next iteration
    }

    // ---- phase 5: fused output — each block writes its own disjoint slice ----
    const int n4  = n >> 2;
    const int cpb = (n4 + NBLK - 1) / NBLK;
    const int gb  = b * cpb;
    const int ge  = min(n4, gb + cpb);
    for (int g = gb + tid; g < ge; g += TPB) {
        int p = g << 2;
        float4 xx = reinterpret_cast<const float4*>(X)[g];
        unsigned bits = (bm[p >> 5] >> (p & 31)) & 0xFu;
        float4 yy;
        yy.x = (bits & 1u) ? v : xx.x;
        yy.y = (bits & 2u) ? v : xx.y;
        yy.z = (bits & 4u) ? v : xx.z;
        yy.w = (bits & 8u) ? v : xx.w;
        reinterpret_cast<float4*>(out)[g] = yy;
    }
    if (b == NBLK - 1) {   // scalar tail (empty for n % 4 == 0)
        for (int p = (n4 << 2) + tid; p < n; p += TPB) {
            bool miss = (bm[p >> 5] >> (p & 31)) & 1u;
            out[p] = miss ? v : X[p];
        }
    }
}

extern "C" void kernel_launch(void* const* d_in, const int* in_sizes, int n_in,
                              void* d_out, int out_size, void* d_ws, size_t ws_size,
                              hipStream_t stream) {
    const float* X        = (const float*)d_in[0];
    const int*   miss_idx = (const int*)d_in[1];
    float*       out      = (float*)d_out;

    const int n_miss = in_sizes[1];
    const int n_obs  = in_sizes[2];
    const int n      = out_size;          // 32768 <= BMW_MAX*32

    knn_all_kernel<<<NBLK, TPB, 0, stream>>>(X, miss_idx, out, n, n_miss, n_obs);
}